// Round 1
// baseline (397.803 us; speedup 1.0000x reference)
//
#include <hip/hip_runtime.h>

// HyenaSE gated causal depthwise conv, fp32.
// B=2, D=4096, L=4096, G=256, HL=128.
// out[b,d,t] = q[b,d,t] * sum_{j=0..127} h[d%G, j] * (k*x)[b,d, t-127+j]

#define HSE_B  2
#define HSE_D  4096
#define HSE_L  4096
#define HSE_G  256
#define HSE_HL 128

constexpr int TPB = 256;           // threads per block (4 waves)
constexpr int VPT = 16;            // consecutive outputs per thread: 256*16 = 4096 = L
constexpr int PAD = 128;           // causal zero pad region in LDS (>= HL-1, float4 aligned)
constexpr int LDS_KX = PAD + HSE_L; // 4224 floats = 16896 B

// XOR swizzle: permutes bank-quads (bits 2..4) using bits 5..7.
// Preserves float4 alignment (only touches bits >= 2, constant within aligned quad).
__device__ __forceinline__ int swiz(int i) {
    return i ^ (((i >> 5) & 7) << 2);
}

__global__ __launch_bounds__(TPB) void hyena_se_kernel(
    const float* __restrict__ x, const float* __restrict__ k,
    const float* __restrict__ q, const float* __restrict__ h,
    float* __restrict__ out)
{
    __shared__ float skx[LDS_KX];
    __shared__ float sh[HSE_HL];

    const int blk = blockIdx.x;            // 0 .. B*D-1, one row per block
    const int d   = blk & (HSE_D - 1);
    const int g   = d & (HSE_G - 1);
    const size_t row = (size_t)blk * HSE_L;
    const int tid = threadIdx.x;

    // --- stage filter (128 floats, contiguous, no swizzle: reads are broadcast) ---
    if (tid < HSE_HL / 4) {
        ((float4*)sh)[tid] = ((const float4*)(h + (size_t)g * HSE_HL))[tid];
    }
    // --- zero causal pad ---
    if (tid < PAD / 4) {
        int idx = 4 * tid;
        ((float4*)skx)[swiz(idx) >> 2] = make_float4(0.f, 0.f, 0.f, 0.f);
    }
    // --- stage kx = k*x into swizzled LDS ---
    #pragma unroll
    for (int r = 0; r < HSE_L / (4 * TPB); ++r) {   // 4 iters
        int pos = 4 * (tid + TPB * r);
        float4 xv = *(const float4*)(x + row + pos);
        float4 kv = *(const float4*)(k + row + pos);
        float4 p = make_float4(xv.x * kv.x, xv.y * kv.y, xv.z * kv.z, xv.w * kv.w);
        ((float4*)skx)[swiz(PAD + pos) >> 2] = p;
    }
    __syncthreads();

    const int t0 = tid * VPT;
    float acc[VPT];
    #pragma unroll
    for (int v = 0; v < VPT; ++v) acc[v] = 0.f;

    // K-loop: 16 chunks of 8 taps.
    // LDS index for output t, tap j' is (PAD + t - 127 + j') = t + j' + 1.
    // Window per chunk: w[p] = skx[t0 + j + p], p = 0..23; use w[1 + v + u].
    #pragma unroll
    for (int jc = 0; jc < HSE_HL / 8; ++jc) {
        const int j = jc * 8;
        float w[24];
        #pragma unroll
        for (int m = 0; m < 6; ++m) {
            float4 wv = ((const float4*)skx)[swiz(t0 + j + 4 * m) >> 2];
            w[4 * m + 0] = wv.x; w[4 * m + 1] = wv.y;
            w[4 * m + 2] = wv.z; w[4 * m + 3] = wv.w;
        }
        float hf[8];
        {
            float4 h0 = ((const float4*)sh)[(j >> 2) + 0];  // broadcast read
            float4 h1 = ((const float4*)sh)[(j >> 2) + 1];
            hf[0] = h0.x; hf[1] = h0.y; hf[2] = h0.z; hf[3] = h0.w;
            hf[4] = h1.x; hf[5] = h1.y; hf[6] = h1.z; hf[7] = h1.w;
        }
        #pragma unroll
        for (int v = 0; v < VPT; ++v) {
            #pragma unroll
            for (int u = 0; u < 8; ++u) {
                acc[v] = fmaf(hf[u], w[1 + v + u], acc[v]);
            }
        }
    }

    // --- epilogue: out = q * acc ---
    #pragma unroll
    for (int m = 0; m < VPT / 4; ++m) {
        float4 qv = *(const float4*)(q + row + t0 + 4 * m);
        float4 o;
        o.x = qv.x * acc[4 * m + 0];
        o.y = qv.y * acc[4 * m + 1];
        o.z = qv.z * acc[4 * m + 2];
        o.w = qv.w * acc[4 * m + 3];
        *(float4*)(out + row + t0 + 4 * m) = o;
    }
}

extern "C" void kernel_launch(void* const* d_in, const int* in_sizes, int n_in,
                              void* d_out, int out_size, void* d_ws, size_t ws_size,
                              hipStream_t stream) {
    const float* x = (const float*)d_in[0];
    const float* k = (const float*)d_in[1];
    const float* q = (const float*)d_in[2];
    const float* h = (const float*)d_in[3];
    float* o = (float*)d_out;

    dim3 grid(HSE_B * HSE_D);
    dim3 block(TPB);
    hyena_se_kernel<<<grid, block, 0, stream>>>(x, k, q, h, o);
}

// Round 2
// 394.002 us; speedup vs baseline: 1.0096x; 1.0096x over previous
//
#include <hip/hip_runtime.h>

// HyenaSE gated causal depthwise conv, fp32.
// B=2, D=4096, L=4096, G=256, HL=128.
// out[b,d,t] = q[b,d,t] * sum_{j=0..127} h[d%G, j] * (k*x)[b,d, t-127+j]
//
// R2: rolling register window (2 LDS reads/chunk instead of 6),
//     filter from scalar cache (wave-uniform h row, SGPR operand in v_fma),
//     q prefetched before the K-loop.

#define HSE_B  2
#define HSE_D  4096
#define HSE_L  4096
#define HSE_G  256
#define HSE_HL 128

constexpr int TPB = 256;            // threads per block (4 waves)
constexpr int VPT = 16;             // consecutive outputs per thread: 256*16 = 4096 = L
constexpr int PAD = 128;            // causal zero pad region (>= HL-1, float4 aligned)
constexpr int LDS_KX = PAD + HSE_L; // 4224 floats = 16896 B

// XOR swizzle: permutes bank-quads (bits 2..4) using bits 5..7.
// Preserves float4 alignment. Makes the stride-16-float read pattern
// (t0 = tid*16) cover all 8 bank-quads per 8 lanes -> conflict-free.
__device__ __forceinline__ int swiz(int i) {
    return i ^ (((i >> 5) & 7) << 2);
}

__global__ __launch_bounds__(TPB) void hyena_se_kernel(
    const float* __restrict__ x, const float* __restrict__ k,
    const float* __restrict__ q, const float* __restrict__ h,
    float* __restrict__ out)
{
    __shared__ float skx[LDS_KX];

    const int blk = blockIdx.x;            // one (b,d) row per block
    const int d   = blk & (HSE_D - 1);
    const int g   = d & (HSE_G - 1);
    const size_t row = (size_t)blk * HSE_L;
    const int tid = threadIdx.x;
    // Wave-uniform filter row -> compiler emits s_load; h values become
    // SGPR operands of v_fma (1 SGPR read per VALU instr is legal).
    const float* __restrict__ hrow = h + (size_t)g * HSE_HL;

    // --- zero causal pad ---
    if (tid < PAD / 4) {
        ((float4*)skx)[swiz(4 * tid) >> 2] = make_float4(0.f, 0.f, 0.f, 0.f);
    }
    // --- stage kx = k*x into swizzled LDS ---
    #pragma unroll
    for (int r = 0; r < HSE_L / (4 * TPB); ++r) {   // 4 iters
        int pos = 4 * (tid + TPB * r);
        float4 xv = *(const float4*)(x + row + pos);
        float4 kv = *(const float4*)(k + row + pos);
        ((float4*)skx)[swiz(PAD + pos) >> 2] =
            make_float4(xv.x * kv.x, xv.y * kv.y, xv.z * kv.z, xv.w * kv.w);
    }

    const int t0 = tid * VPT;

    // --- prefetch q for the epilogue (latency overlaps the K-loop) ---
    float4 qv[VPT / 4];
    #pragma unroll
    for (int m = 0; m < VPT / 4; ++m)
        qv[m] = *(const float4*)(q + row + t0 + 4 * m);

    __syncthreads();

    float acc[VPT];
    #pragma unroll
    for (int v = 0; v < VPT; ++v) acc[v] = 0.f;

    // Rolling window w[] over LDS indices [t0 + 8*jc, t0 + 8*jc + 24).
    // LDS index for output t=t0+v, tap j=8*jc+u is t + j + 1 -> w[1+v+u].
    float w[24];
    #pragma unroll
    for (int m = 0; m < 4; ++m) {
        float4 wv = ((const float4*)skx)[swiz(t0 + 4 * m) >> 2];
        w[4*m+0] = wv.x; w[4*m+1] = wv.y; w[4*m+2] = wv.z; w[4*m+3] = wv.w;
    }

    #pragma unroll
    for (int jc = 0; jc < HSE_HL / 8; ++jc) {
        // 8 new window floats (2 conflict-free b128 reads)
        #pragma unroll
        for (int m = 0; m < 2; ++m) {
            float4 wv = ((const float4*)skx)[swiz(t0 + 8 * jc + 16 + 4 * m) >> 2];
            w[16 + 4*m + 0] = wv.x; w[16 + 4*m + 1] = wv.y;
            w[16 + 4*m + 2] = wv.z; w[16 + 4*m + 3] = wv.w;
        }
        // 8 filter taps from scalar cache (uniform address)
        float hf[8];
        #pragma unroll
        for (int u = 0; u < 8; ++u) hf[u] = hrow[8 * jc + u];

        #pragma unroll
        for (int v = 0; v < VPT; ++v) {
            #pragma unroll
            for (int u = 0; u < 8; ++u) {
                acc[v] = fmaf(hf[u], w[1 + v + u], acc[v]);
            }
        }
        // slide window by 8 (register renaming after full unroll: free)
        #pragma unroll
        for (int p = 0; p < 16; ++p) w[p] = w[p + 8];
    }

    // --- epilogue: out = q * acc ---
    #pragma unroll
    for (int m = 0; m < VPT / 4; ++m) {
        float4 o;
        o.x = qv[m].x * acc[4*m + 0];
        o.y = qv[m].y * acc[4*m + 1];
        o.z = qv[m].z * acc[4*m + 2];
        o.w = qv[m].w * acc[4*m + 3];
        *(float4*)(out + row + t0 + 4 * m) = o;
    }
}

extern "C" void kernel_launch(void* const* d_in, const int* in_sizes, int n_in,
                              void* d_out, int out_size, void* d_ws, size_t ws_size,
                              hipStream_t stream) {
    const float* x = (const float*)d_in[0];
    const float* k = (const float*)d_in[1];
    const float* q = (const float*)d_in[2];
    const float* h = (const float*)d_in[3];
    float* o = (float*)d_out;

    dim3 grid(HSE_B * HSE_D);
    dim3 block(TPB);
    hyena_se_kernel<<<grid, block, 0, stream>>>(x, k, q, h, o);
}